// Round 12
// baseline (131.667 us; speedup 1.0000x reference)
//
#include <hip/hip_runtime.h>
#include <stdint.h>
#include <math.h>

using u16    = unsigned short;
using short8 = __attribute__((ext_vector_type(8))) short;
using f32x4  = __attribute__((ext_vector_type(4))) float;
using f32x16 = __attribute__((ext_vector_type(16))) float;
using u32x4  = __attribute__((ext_vector_type(4))) uint32_t;

#define DEVI __device__ __forceinline__
#define FENCE asm volatile("" ::: "memory")
#define GPTR(p) ((const __attribute__((address_space(1))) uint32_t*)(p))
#define LPTR(p) ((__attribute__((address_space(3))) uint32_t*)(p))

static constexpr int S  = 2048;
static constexpr int D  = 512;
static constexpr int DH = 64;
// log2(e)/sqrt(512): folded into the Q projection output
static constexpr float C2 = 0.063763906f;

DEVI u16 f2bf(float f){
  uint32_t u = __float_as_uint(f);
  u = u + 0x7FFFu + ((u >> 16) & 1u);   // RNE
  return (u16)(u >> 16);
}

DEVI uint32_t cvt_pk_bf16(float a, float b){
  uint32_t d;
  asm("v_cvt_pk_bf16_f32 %0, %1, %2" : "=v"(d) : "v"(a), "v"(b));
  return d;
}

// ---------------- weight fp32 -> bf16 (wq|wk|wv|wo contiguous) ----------------
__global__ void k_cvtw(const float* __restrict__ a, const float* __restrict__ b,
                       const float* __restrict__ c, const float* __restrict__ d,
                       u16* __restrict__ out){
  int i = blockIdx.x * blockDim.x + threadIdx.x;
  int sel = i >> 16;
  const float* src = sel == 0 ? a : sel == 1 ? b : sel == 2 ? c : d;
  float4 v = reinterpret_cast<const float4*>(src)[i & ((1<<16)-1)];
  uint2 o;
  o.x = (uint32_t)f2bf(v.x) | ((uint32_t)f2bf(v.y) << 16);
  o.y = (uint32_t)f2bf(v.z) | ((uint32_t)f2bf(v.w) << 16);
  reinterpret_cast<uint2*>(out)[i] = o;
}

// ---------------- QKV projection GEMM: depth-2 A register pipeline ----------------
// z=0: Q (oscale=C2) ; z=1: K ; z=2: V (transposed out)
__global__ __launch_bounds__(512)
void k_gemm_qkv(const float* __restrict__ Xq, const float* __restrict__ Xk,
                const float* __restrict__ Xv, const u16* __restrict__ Wall,
                const float* __restrict__ bq, const float* __restrict__ bk,
                const float* __restrict__ bv,
                u16* __restrict__ Qp, u16* __restrict__ Kp, u16* __restrict__ Vtp)
{
  __shared__ __align__(16) u16 As[2][128*64];
  __shared__ __align__(16) u16 Bs[2][128*64];
  const int tid = threadIdx.x;
  const int w = tid >> 6, l = tid & 63;
  const int wm = w & 3, wn = w >> 2;
  const int m0 = blockIdx.x * 128, n0 = blockIdx.y * 128;
  const int z = blockIdx.z;
  const int srow = l >> 3, sslot = l & 7;

  const float* X = z == 0 ? Xq : (z == 1 ? Xk : Xv);
  const u16*   W = Wall + (size_t)z * 512 * 512;
  const float* bias = z == 0 ? bq : (z == 1 ? bk : bv);
  const float oscale = z == 0 ? C2 : 1.0f;

  const int arow = tid >> 2;            // 0..127
  const int ac   = (tid & 3) * 16;      // col base (of 64)

  f32x4 acc[2][4];
  #pragma unroll
  for (int i = 0; i < 2; i++)
    #pragma unroll
    for (int j = 0; j < 4; j++)
      #pragma unroll
      for (int r = 0; r < 4; r++) acc[i][j][r] = 0.f;

  float4 av[2][4];
  auto LOADA = [&](int p, int kt){
    #pragma unroll
    for (int j = 0; j < 4; j++)
      av[p][j] = *reinterpret_cast<const float4*>(&X[(long)(m0 + arow)*D + kt + ac + j*4]);
  };
  auto WRITEA = [&](int buf, int p){
    #pragma unroll
    for (int j2 = 0; j2 < 2; j2++){
      u32x4 pkv;
      pkv[0] = cvt_pk_bf16(av[p][2*j2].x,   av[p][2*j2].y);
      pkv[1] = cvt_pk_bf16(av[p][2*j2].z,   av[p][2*j2].w);
      pkv[2] = cvt_pk_bf16(av[p][2*j2+1].x, av[p][2*j2+1].y);
      pkv[3] = cvt_pk_bf16(av[p][2*j2+1].z, av[p][2*j2+1].w);
      int slot = ((ac >> 3) + j2) ^ (arow & 7);
      *reinterpret_cast<u32x4*>(&As[buf][arow*64 + slot*8]) = pkv;
    }
  };
  auto STAGEB = [&](int buf, int kt){
    #pragma unroll
    for (int i = 0; i < 2; i++){
      int r = w*16 + i*8 + srow;
      int scol = (sslot ^ (r & 7)) * 8;
      __builtin_amdgcn_global_load_lds(GPTR(W + (long)(n0 + r)*D + kt + scol),
                                       LPTR(&Bs[buf][(w*16 + i*8)*64]), 16, 0, 0);
    }
  };

  // prologue: tile0 A -> LDS, tile1 A -> regs, tile0 B staged
  LOADA(0, 0);
  STAGEB(0, 0);
  WRITEA(0, 0);                 // compiler waits av[0]
  LOADA(1, 64);                 // tile1 A in flight across barrier
  asm volatile("s_waitcnt vmcnt(4) lgkmcnt(0)" ::: "memory");
  __builtin_amdgcn_s_barrier();
  FENCE;

  #pragma unroll
  for (int t = 0; t < 8; t++){
    const int buf = t & 1;
    if (t < 7) STAGEB(buf ^ 1, (t+1)*64);
    if (t < 6) LOADA(t & 1, (t+2)*64);      // av[t&1] held tile t (already in LDS)
    #pragma unroll
    for (int ks = 0; ks < 2; ks++){
      short8 af[2];
      #pragma unroll
      for (int mf = 0; mf < 2; mf++){
        int row = wm*32 + mf*16 + (l & 15);
        int cw = (ks*4 + (l >> 4)) ^ (row & 7);
        af[mf] = *reinterpret_cast<const short8*>(&As[buf][(row*8 + cw)*8]);
      }
      #pragma unroll
      for (int nf = 0; nf < 4; nf++){
        int row = wn*64 + nf*16 + (l & 15);
        int cw = (ks*4 + (l >> 4)) ^ (row & 7);
        short8 bf = *reinterpret_cast<const short8*>(&Bs[buf][(row*8 + cw)*8]);
        #pragma unroll
        for (int mf = 0; mf < 2; mf++)
          acc[mf][nf] = __builtin_amdgcn_mfma_f32_16x16x32_bf16(af[mf], bf, acc[mf][nf], 0, 0, 0);
      }
    }
    if (t < 7) WRITEA(buf ^ 1, (t+1) & 1);  // data loaded a full iter ago
    if (t < 6)      asm volatile("s_waitcnt vmcnt(4) lgkmcnt(0)" ::: "memory");
    else if (t == 6) asm volatile("s_waitcnt vmcnt(0) lgkmcnt(0)" ::: "memory");
    if (t < 7){ __builtin_amdgcn_s_barrier(); FENCE; }
  }

  #pragma unroll
  for (int mf = 0; mf < 2; mf++){
    #pragma unroll
    for (int nf = 0; nf < 4; nf++){
      int n = n0 + wn*64 + nf*16 + (l & 15);
      float bi = bias[n];
      int h_ = n >> 6, d_ = n & 63;
      if (z == 2){
        int mb = m0 + wm*32 + mf*16 + (l >> 4)*4;
        int b_ = mb >> 11, s_ = mb & 2047;
        uint2 o;
        o.x = (uint32_t)f2bf(acc[mf][nf][0] + bi) | ((uint32_t)f2bf(acc[mf][nf][1] + bi) << 16);
        o.y = (uint32_t)f2bf(acc[mf][nf][2] + bi) | ((uint32_t)f2bf(acc[mf][nf][3] + bi) << 16);
        *reinterpret_cast<uint2*>(&Vtp[((long)((b_*8 + h_)*64 + d_))*2048 + s_]) = o;
      } else {
        u16* outp = z == 0 ? Qp : Kp;
        #pragma unroll
        for (int r = 0; r < 4; r++){
          int m = m0 + wm*32 + mf*16 + (l >> 4)*4 + r;
          int b_ = m >> 11, s_ = m & 2047;
          outp[((long)((b_*8 + h_)*2048 + s_))*64 + d_] = f2bf((acc[mf][nf][r] + bi)*oscale);
        }
      }
    }
  }
}

// ---------------- output GEMM: 3-buffer counted-vmcnt pipeline ----------------
__global__ __launch_bounds__(512)
void k_gemm_ao(const u16* __restrict__ A, const u16* __restrict__ W,
               const float* __restrict__ bias2, float* __restrict__ outp)
{
  __shared__ __align__(16) u16 As[3][128*64];
  __shared__ __align__(16) u16 Bs[3][128*64];
  const int tid = threadIdx.x;
  const int w = tid >> 6, l = tid & 63;
  const int wm = w & 3, wn = w >> 2;
  const int m0 = blockIdx.x * 128, n0 = blockIdx.y * 128;
  const int srow = l >> 3, sslot = l & 7;

  f32x4 acc[2][4];
  #pragma unroll
  for (int i = 0; i < 2; i++)
    #pragma unroll
    for (int j = 0; j < 4; j++)
      #pragma unroll
      for (int r = 0; r < 4; r++) acc[i][j][r] = 0.f;

  auto STAGE = [&](int buf, int kt){
    #pragma unroll
    for (int i = 0; i < 2; i++){
      int r = w*16 + i*8 + srow;
      int scol = (sslot ^ (r & 7)) * 8;
      int m = m0 + r, k = kt + scol;
      long ga = ((long)(((m >> 11)*8 + (k >> 6))*2048 + (m & 2047)))*64 + (k & 63);
      __builtin_amdgcn_global_load_lds(GPTR(A + ga), LPTR(&As[buf][(w*16 + i*8)*64]), 16, 0, 0);
      long gb = (long)(n0 + r)*D + kt + scol;
      __builtin_amdgcn_global_load_lds(GPTR(W + gb), LPTR(&Bs[buf][(w*16 + i*8)*64]), 16, 0, 0);
    }
  };

  STAGE(0, 0); STAGE(1, 64);
  asm volatile("s_waitcnt vmcnt(4)" ::: "memory");
  __builtin_amdgcn_s_barrier();
  FENCE;

  #pragma unroll
  for (int t = 0; t < 8; t++){
    const int buf = t % 3;
    if (t + 2 < 8) STAGE((t + 2) % 3, (t + 2)*64);
    #pragma unroll
    for (int ks = 0; ks < 2; ks++){
      short8 af[2];
      #pragma unroll
      for (int mf = 0; mf < 2; mf++){
        int row = wm*32 + mf*16 + (l & 15);
        int cw = (ks*4 + (l >> 4)) ^ (row & 7);
        af[mf] = *reinterpret_cast<const short8*>(&As[buf][(row*8 + cw)*8]);
      }
      #pragma unroll
      for (int nf = 0; nf < 4; nf++){
        int row = wn*64 + nf*16 + (l & 15);
        int cw = (ks*4 + (l >> 4)) ^ (row & 7);
        short8 bf = *reinterpret_cast<const short8*>(&Bs[buf][(row*8 + cw)*8]);
        #pragma unroll
        for (int mf = 0; mf < 2; mf++)
          acc[mf][nf] = __builtin_amdgcn_mfma_f32_16x16x32_bf16(af[mf], bf, acc[mf][nf], 0, 0, 0);
      }
    }
    if (t < 7){
      if (t < 6) asm volatile("s_waitcnt vmcnt(4)" ::: "memory");
      else       asm volatile("s_waitcnt vmcnt(0)" ::: "memory");
      __builtin_amdgcn_s_barrier();
      FENCE;
    }
  }

  #pragma unroll
  for (int mf = 0; mf < 2; mf++)
    #pragma unroll
    for (int nf = 0; nf < 4; nf++){
      int n = n0 + wn*64 + nf*16 + (l & 15);
      float bi = bias2[(m0 >> 11)*512 + n];
      #pragma unroll
      for (int r = 0; r < 4; r++){
        int m = m0 + wm*32 + mf*16 + (l >> 4)*4 + r;
        outp[(long)m*D + n] = acc[mf][nf][r] + bi;
      }
    }
}

// ---------------- SV[bh][d] = sum_t Vt[bh][d][t] ----------------
__global__ __launch_bounds__(256)
void k_sumv(const u16* __restrict__ Vt, float* __restrict__ SV){
  const int w = threadIdx.x >> 6, l = threadIdx.x & 63;
  const int row = blockIdx.x*4 + w;
  const u16* src = Vt + (long)row * S;
  float s = 0.f;
  #pragma unroll
  for (int j = 0; j < 4; j++){
    short8 v = *reinterpret_cast<const short8*>(&src[j*512 + l*8]);
    #pragma unroll
    for (int e = 0; e < 8; e++)
      s += __uint_as_float(((uint32_t)(u16)v[e]) << 16);
  }
  #pragma unroll
  for (int m = 1; m < 64; m <<= 1) s += __shfl_xor(s, m, 64);
  if (l == 0) SV[row] = s;
}

// ---------------- bias2[b][n] = bo[n] + 0.5 * sum_k SV[b][k]*Wo[n][k] ----------------
__global__ __launch_bounds__(256)
void k_bias2(const float* __restrict__ SV, const float* __restrict__ Wo,
             const float* __restrict__ bo, float* __restrict__ bias2){
  const int w = threadIdx.x >> 6, l = threadIdx.x & 63;
  const int idx = blockIdx.x*4 + w;
  const int b = idx >> 9, n = idx & 511;
  float dot = 0.f;
  #pragma unroll
  for (int j = 0; j < 2; j++){
    float4 wv = *reinterpret_cast<const float4*>(&Wo[(long)n*512 + l*8 + j*4]);
    float4 sv = *reinterpret_cast<const float4*>(&SV[b*512 + l*8 + j*4]);
    dot += wv.x*sv.x + wv.y*sv.y + wv.z*sv.z + wv.w*sv.w;
  }
  #pragma unroll
  for (int m = 1; m < 64; m <<= 1) dot += __shfl_xor(dot, m, 64);
  if (l == 0) bias2[idx] = bo[n] + 0.5f * dot;
}

// ================ flash: paf-pipelined, macro codegen (no refs -> no scratch) ================
// AO = 0.25 * softmax(K.(Q*C2)) V ; 512 blocks = bh(32 fastest) x qt(16 of 128 rows)
// body(t): vmcnt(2); barrier; STAGE(t+2); QK(t); PV(t-1)[indep MFMA || EXP]; EXPPACK(t)
// paf double-buffered by NAME (pafA*/pafB*), parity fully static. sacc is body-local.

#define MFMA32(A_, B_, C_) __builtin_amdgcn_mfma_f32_32x32x16_bf16(A_, B_, C_, 0, 0, 0)

#define QKM(BUF_, SACC_) { \
    const u16* KT_ = KB + (BUF_)*2048; \
    short8 k0_ = *reinterpret_cast<const short8*>(KT_ + koff[0]); \
    short8 k1_ = *reinterpret_cast<const short8*>(KT_ + koff[1]); \
    short8 k2_ = *reinterpret_cast<const short8*>(KT_ + koff[2]); \
    short8 k3_ = *reinterpret_cast<const short8*>(KT_ + koff[3]); \
    __builtin_amdgcn_s_setprio(1); \
    SACC_ = MFMA32(k0_, qfr[0], SACC_); \
    SACC_ = MFMA32(k1_, qfr[1], SACC_); \
    SACC_ = MFMA32(k2_, qfr[2], SACC_); \
    SACC_ = MFMA32(k3_, qfr[3], SACC_); \
    __builtin_amdgcn_s_setprio(0); }

#define PVM(BUF_, P0_, P1_) { \
    const u16* VT_ = VB + (BUF_)*2048; \
    short8 v0_ = *reinterpret_cast<const short8*>(VT_ + voff[0]); \
    short8 v1_ = *reinterpret_cast<const short8*>(VT_ + voff[1]); \
    short8 v2_ = *reinterpret_cast<const short8*>(VT_ + voff[2]); \
    short8 v3_ = *reinterpret_cast<const short8*>(VT_ + voff[3]); \
    __builtin_amdgcn_s_setprio(1); \
    oacc0 = MFMA32(P0_, v0_, oacc0); \
    oacc1 = MFMA32(P0_, v1_, oacc1); \
    oacc0 = MFMA32(P1_, v2_, oacc0); \
    oacc1 = MFMA32(P1_, v3_, oacc1); \
    __builtin_amdgcn_s_setprio(0); }

#define EXPM(SACC_, P0_, P1_) { \
    uint32_t pk_[8]; float s0_ = 0.f, s1_ = 0.f; \
    _Pragma("unroll") \
    for (int j_ = 0; j_ < 8; j_++){ \
      float e0_ = __builtin_amdgcn_exp2f(SACC_[2*j_]); \
      float e1_ = __builtin_amdgcn_exp2f(SACC_[2*j_+1]); \
      if (j_ & 1) s1_ += e0_ + e1_; else s0_ += e0_ + e1_; \
      pk_[j_] = cvt_pk_bf16(e0_, e1_); \
    } \
    lsum += s0_ + s1_; \
    { auto q1_ = __builtin_amdgcn_permlane32_swap(pk_[0], pk_[2], false, false); \
      auto q2_ = __builtin_amdgcn_permlane32_swap(pk_[1], pk_[3], false, false); \
      u32x4 a_ = { (uint32_t)q1_[0], (uint32_t)q2_[0], (uint32_t)q1_[1], (uint32_t)q2_[1] }; \
      P0_ = __builtin_bit_cast(short8, a_); } \
    { auto q1_ = __builtin_amdgcn_permlane32_swap(pk_[4], pk_[6], false, false); \
      auto q2_ = __builtin_amdgcn_permlane32_swap(pk_[5], pk_[7], false, false); \
      u32x4 a_ = { (uint32_t)q1_[0], (uint32_t)q2_[0], (uint32_t)q1_[1], (uint32_t)q2_[1] }; \
      P1_ = __builtin_bit_cast(short8, a_); } }

#define BODYM(VMC_, DOSTG_, QB_, PVB_, PE0_, PE1_, PP0_, PP1_) { \
    asm volatile("s_waitcnt vmcnt(" VMC_ ")" ::: "memory"); \
    __builtin_amdgcn_s_barrier(); \
    FENCE; \
    if (DOSTG_) STAGE(((QB_) + 2) & 3); \
    f32x16 sacc_ = {0.f,0.f,0.f,0.f,0.f,0.f,0.f,0.f,0.f,0.f,0.f,0.f,0.f,0.f,0.f,0.f}; \
    QKM(QB_, sacc_); \
    PVM(PVB_, PP0_, PP1_); \
    EXPM(sacc_, PE0_, PE1_); }

__global__ __launch_bounds__(512, 4)
void k_flash(const u16* __restrict__ Qp, const u16* __restrict__ Kp,
             const u16* __restrict__ Vt, u16* __restrict__ AO)
{
  __shared__ __align__(16) u16 Ks[2][4][32*64];   // [group][buf] 32 keys x 64 d
  __shared__ __align__(16) u16 Vs[2][4][64*32];   // [group][buf] 64 d x 32 keys
  const int tid = threadIdx.x, w = tid >> 6, l = tid & 63;
  const int g = w >> 2, w4 = w & 3;
  const int bh = blockIdx.x & 31, qt = blockIdx.x >> 5;   // qt 0..15
  const u16* Qb = Qp + (long)bh * S * DH;
  const int hi = l >> 5, ln = l & 31;

  short8 qfr[4];   // Q*C2 (scale folded in projection)
  #pragma unroll
  for (int c = 0; c < 4; c++){
    int row = qt*128 + w4*32 + ln;
    qfr[c] = *reinterpret_cast<const short8*>(&Qb[(long)row*DH + c*16 + hi*8]);
  }

  // lane-constant LDS read offsets (u16 units within one buf)
  int koff[4], voff[4];
  #pragma unroll
  for (int c = 0; c < 4; c++)
    koff[c] = ln*64 + (((2*c + hi) ^ ((ln ^ (ln >> 3)) & 7))*8);
  #pragma unroll
  for (int ch = 0; ch < 2; ch++)
    #pragma unroll
    for (int nf = 0; nf < 2; nf++){
      int row = nf*32 + ln;
      voff[ch*2 + nf] = row*32 + (((2*ch + hi) ^ ((row ^ (row >> 2)) & 3))*8);
    }

  // staging: source offsets folded into the walking pointers
  const int rK = w4*8 + (l >> 3), sK = l & 7;
  const int rV = w4*16 + (l >> 2), sV = l & 3;
  const u16* kptr = Kp + (long)bh*S*DH + g*2048
                  + (long)rK*64 + ((sK ^ ((rK ^ (rK >> 3)) & 7))*8);
  const u16* vptr = Vt + (long)bh*DH*S + g*32
                  + (long)rV*S  + ((sV ^ ((rV ^ (rV >> 2)) & 3))*8);

  auto STAGE = [&](int buf){
    __builtin_amdgcn_global_load_lds(GPTR(kptr), LPTR(&Ks[g][buf][w4*512]), 16, 0, 0);
    __builtin_amdgcn_global_load_lds(GPTR(vptr), LPTR(&Vs[g][buf][w4*512]), 16, 0, 0);
    kptr += 4096;   // next tile for this group (64 keys forward)
    vptr += 64;
  };

  f32x16 oacc0, oacc1;
  #pragma unroll
  for (int r = 0; r < 16; r++){ oacc0[r] = 0.f; oacc1[r] = 0.f; }
  float lsum = 0.f;
  short8 pafA0, pafA1, pafB0, pafB1;

  const u16* KB = &Ks[g][0][0];
  const u16* VB = &Vs[g][0][0];

  // prologue: depth-2 prefetch; t=0 (even): QK, EXP -> pafA (no PV)
  STAGE(0); STAGE(1);
  asm volatile("s_waitcnt vmcnt(2)" ::: "memory");
  __builtin_amdgcn_s_barrier();
  FENCE;
  STAGE(2);
  {
    f32x16 sacc_ = {0.f,0.f,0.f,0.f,0.f,0.f,0.f,0.f,0.f,0.f,0.f,0.f,0.f,0.f,0.f,0.f};
    QKM(0, sacc_);
    EXPM(sacc_, pafA0, pafA1);
  }

  // main loop: t = 1..28 (7 chunks of 4; buf pattern 1,2,3,0; parity O,E,O,E)
  #pragma unroll 1
  for (int tb = 0; tb < 7; tb++){
    BODYM("2", true, 1, 0, pafB0, pafB1, pafA0, pafA1);   // t odd : EXP->B, PV uses A
    BODYM("2", true, 2, 1, pafA0, pafA1, pafB0, pafB1);   // t even: EXP->A, PV uses B
    BODYM("2", true, 3, 2, pafB0, pafB1, pafA0, pafA1);
    BODYM("2", true, 0, 3, pafA0, pafA1, pafB0, pafB1);
  }
  // tail: t=29 (odd, buf 1, stage 31), t=30 (even, buf 2), t=31 (odd, buf 3)
  BODYM("2", true,  1, 0, pafB0, pafB1, pafA0, pafA1);    // t=29
  BODYM("2", false, 2, 1, pafA0, pafA1, pafB0, pafB1);    // t=30
  BODYM("0", false, 3, 2, pafB0, pafB1, pafA0, pafA1);    // t=31
  PVM(3, pafB0, pafB1);                                   // PV(31)

  __syncthreads();   // all compute done before LDS reuse

  // cross-group combine in LDS
  lsum += __shfl_xor(lsum, 32, 64);
  float* OB = (float*)Ks;    // 4 waves x 32 qrow x 64 d = 32 KB
  float* LB = (float*)Vs;
  if (g == 1){
    #pragma unroll
    for (int r = 0; r < 16; r++){
      int qrow = (r & 3) + 8*(r >> 2) + 4*hi;
      OB[w4*2048 + qrow*64 + ln]      = oacc0[r];
      OB[w4*2048 + qrow*64 + 32 + ln] = oacc1[r];
    }
    if (hi == 0) LB[w4*32 + ln] = lsum;
  }
  __syncthreads();
  if (g == 0){
    float l2 = LB[w4*32 + ln];
    float linv = 0.25f / (lsum + l2);   // valid for qrow = ln
    #pragma unroll
    for (int r = 0; r < 16; r++){
      int qrow = (r & 3) + 8*(r >> 2) + 4*hi;
      float sc = __shfl(linv, qrow, 64);
      int s_ = qt*128 + w4*32 + qrow;
      float o0 = oacc0[r] + OB[w4*2048 + qrow*64 + ln];
      float o1 = oacc1[r] + OB[w4*2048 + qrow*64 + 32 + ln];
      AO[((long)bh*S + s_)*DH + ln]      = f2bf(o0 * sc);
      AO[((long)bh*S + s_)*DH + 32 + ln] = f2bf(o1 * sc);
    }
  }
}

// ---------------- launch ----------------
extern "C" void kernel_launch(void* const* d_in, const int* in_sizes, int n_in,
                              void* d_out, int out_size, void* d_ws, size_t ws_size,
                              hipStream_t stream)
{
  const float* query = (const float*)d_in[0];
  const float* key_  = (const float*)d_in[1];
  const float* value = (const float*)d_in[2];
  const float* Wq = (const float*)d_in[3];
  const float* bq = (const float*)d_in[4];
  const float* Wk = (const float*)d_in[5];
  const float* bk = (const float*)d_in[6];
  const float* Wv = (const float*)d_in[7];
  const float* bv = (const float*)d_in[8];
  const float* Wo = (const float*)d_in[9];
  const float* bo = (const float*)d_in[10];

  char* ws = (char*)d_ws;
  const size_t XSZ = (size_t)8192 * 512 * 2;   // 8 MiB
  const size_t WSZ = (size_t)512 * 512 * 2;    // 512 KiB
  u16* AO  = (u16*)(ws);
  u16* wqb = (u16*)(ws + XSZ);                 // wq|wk|wv|wo contiguous
  u16* wob = (u16*)(ws + XSZ + 3*WSZ);
  u16* Qp  = (u16*)(ws + XSZ + 4*WSZ);
  u16* Kp  = (u16*)(ws + 2*XSZ + 4*WSZ);
  u16* Vtp = (u16*)(ws + 3*XSZ + 4*WSZ);
  float* SV    = (float*)(ws + 4*XSZ + 4*WSZ);
  float* bias2 = (float*)(ws + 4*XSZ + 4*WSZ + 8192);

  k_cvtw<<<(4<<16)/256, 256, 0, stream>>>(Wq, Wk, Wv, Wo, wqb);

  dim3 gq(64, 4, 3);
  k_gemm_qkv<<<gq, 512, 0, stream>>>(query, key_, value, wqb, bq, bk, bv, Qp, Kp, Vtp);

  k_sumv <<<512, 256, 0, stream>>>(Vtp, SV);
  k_bias2<<<512, 256, 0, stream>>>(SV, Wo, bo, bias2);

  k_flash<<<512, 512, 0, stream>>>(Qp, Kp, Vtp, AO);

  dim3 gg(64, 4);
  k_gemm_ao<<<gg, 512, 0, stream>>>(AO, wob, bias2, (float*)d_out);
}

// Round 13
// 92.222 us; speedup vs baseline: 1.4277x; 1.4277x over previous
//
#include <hip/hip_runtime.h>
#include <stdint.h>
#include <math.h>

using u16    = unsigned short;
using short8 = __attribute__((ext_vector_type(8))) short;
using f32x4  = __attribute__((ext_vector_type(4))) float;
using f32x16 = __attribute__((ext_vector_type(16))) float;
using u32x4  = __attribute__((ext_vector_type(4))) uint32_t;

#define DEVI __device__ __forceinline__
#define FENCE asm volatile("" ::: "memory")
#define GPTR(p) ((const __attribute__((address_space(1))) uint32_t*)(p))
#define LPTR(p) ((__attribute__((address_space(3))) uint32_t*)(p))

static constexpr int S  = 2048;
static constexpr int D  = 512;
static constexpr int DH = 64;
// log2(e)/sqrt(512): folded into the Q projection output
static constexpr float C2 = 0.063763906f;

DEVI u16 f2bf(float f){
  uint32_t u = __float_as_uint(f);
  u = u + 0x7FFFu + ((u >> 16) & 1u);   // RNE
  return (u16)(u >> 16);
}

DEVI uint32_t cvt_pk_bf16(float a, float b){
  uint32_t d;
  asm("v_cvt_pk_bf16_f32 %0, %1, %2" : "=v"(d) : "v"(a), "v"(b));
  return d;
}

// ---------------- weight fp32 -> bf16 (wq|wk|wv|wo contiguous) ----------------
__global__ void k_cvtw(const float* __restrict__ a, const float* __restrict__ b,
                       const float* __restrict__ c, const float* __restrict__ d,
                       u16* __restrict__ out){
  int i = blockIdx.x * blockDim.x + threadIdx.x;
  int sel = i >> 16;
  const float* src = sel == 0 ? a : sel == 1 ? b : sel == 2 ? c : d;
  float4 v = reinterpret_cast<const float4*>(src)[i & ((1<<16)-1)];
  uint2 o;
  o.x = (uint32_t)f2bf(v.x) | ((uint32_t)f2bf(v.y) << 16);
  o.y = (uint32_t)f2bf(v.z) | ((uint32_t)f2bf(v.w) << 16);
  reinterpret_cast<uint2*>(out)[i] = o;
}

// ---------------- QKV projection GEMM: depth-2 A register pipeline ----------------
// z=0: Q (oscale=C2) ; z=1: K ; z=2: V (transposed out)
__global__ __launch_bounds__(512)
void k_gemm_qkv(const float* __restrict__ Xq, const float* __restrict__ Xk,
                const float* __restrict__ Xv, const u16* __restrict__ Wall,
                const float* __restrict__ bq, const float* __restrict__ bk,
                const float* __restrict__ bv,
                u16* __restrict__ Qp, u16* __restrict__ Kp, u16* __restrict__ Vtp)
{
  __shared__ __align__(16) u16 As[2][128*64];
  __shared__ __align__(16) u16 Bs[2][128*64];
  const int tid = threadIdx.x;
  const int w = tid >> 6, l = tid & 63;
  const int wm = w & 3, wn = w >> 2;
  const int m0 = blockIdx.x * 128, n0 = blockIdx.y * 128;
  const int z = blockIdx.z;
  const int srow = l >> 3, sslot = l & 7;

  const float* X = z == 0 ? Xq : (z == 1 ? Xk : Xv);
  const u16*   W = Wall + (size_t)z * 512 * 512;
  const float* bias = z == 0 ? bq : (z == 1 ? bk : bv);
  const float oscale = z == 0 ? C2 : 1.0f;

  const int arow = tid >> 2;            // 0..127
  const int ac   = (tid & 3) * 16;      // col base (of 64)

  f32x4 acc[2][4];
  #pragma unroll
  for (int i = 0; i < 2; i++)
    #pragma unroll
    for (int j = 0; j < 4; j++)
      #pragma unroll
      for (int r = 0; r < 4; r++) acc[i][j][r] = 0.f;

  float4 av[2][4];
  auto LOADA = [&](int p, int kt){
    #pragma unroll
    for (int j = 0; j < 4; j++)
      av[p][j] = *reinterpret_cast<const float4*>(&X[(long)(m0 + arow)*D + kt + ac + j*4]);
  };
  auto WRITEA = [&](int buf, int p){
    #pragma unroll
    for (int j2 = 0; j2 < 2; j2++){
      u32x4 pkv;
      pkv[0] = cvt_pk_bf16(av[p][2*j2].x,   av[p][2*j2].y);
      pkv[1] = cvt_pk_bf16(av[p][2*j2].z,   av[p][2*j2].w);
      pkv[2] = cvt_pk_bf16(av[p][2*j2+1].x, av[p][2*j2+1].y);
      pkv[3] = cvt_pk_bf16(av[p][2*j2+1].z, av[p][2*j2+1].w);
      int slot = ((ac >> 3) + j2) ^ (arow & 7);
      *reinterpret_cast<u32x4*>(&As[buf][arow*64 + slot*8]) = pkv;
    }
  };
  auto STAGEB = [&](int buf, int kt){
    #pragma unroll
    for (int i = 0; i < 2; i++){
      int r = w*16 + i*8 + srow;
      int scol = (sslot ^ (r & 7)) * 8;
      __builtin_amdgcn_global_load_lds(GPTR(W + (long)(n0 + r)*D + kt + scol),
                                       LPTR(&Bs[buf][(w*16 + i*8)*64]), 16, 0, 0);
    }
  };

  // prologue: tile0 A -> LDS, tile1 A -> regs, tile0 B staged
  LOADA(0, 0);
  STAGEB(0, 0);
  WRITEA(0, 0);                 // compiler waits av[0]
  LOADA(1, 64);                 // tile1 A in flight across barrier
  asm volatile("s_waitcnt vmcnt(4) lgkmcnt(0)" ::: "memory");
  __builtin_amdgcn_s_barrier();
  FENCE;

  #pragma unroll
  for (int t = 0; t < 8; t++){
    const int buf = t & 1;
    if (t < 7) STAGEB(buf ^ 1, (t+1)*64);
    if (t < 6) LOADA(t & 1, (t+2)*64);      // av[t&1] held tile t (already in LDS)
    #pragma unroll
    for (int ks = 0; ks < 2; ks++){
      short8 af[2];
      #pragma unroll
      for (int mf = 0; mf < 2; mf++){
        int row = wm*32 + mf*16 + (l & 15);
        int cw = (ks*4 + (l >> 4)) ^ (row & 7);
        af[mf] = *reinterpret_cast<const short8*>(&As[buf][(row*8 + cw)*8]);
      }
      #pragma unroll
      for (int nf = 0; nf < 4; nf++){
        int row = wn*64 + nf*16 + (l & 15);
        int cw = (ks*4 + (l >> 4)) ^ (row & 7);
        short8 bf = *reinterpret_cast<const short8*>(&Bs[buf][(row*8 + cw)*8]);
        #pragma unroll
        for (int mf = 0; mf < 2; mf++)
          acc[mf][nf] = __builtin_amdgcn_mfma_f32_16x16x32_bf16(af[mf], bf, acc[mf][nf], 0, 0, 0);
      }
    }
    if (t < 7) WRITEA(buf ^ 1, (t+1) & 1);  // data loaded a full iter ago
    if (t < 6)      asm volatile("s_waitcnt vmcnt(4) lgkmcnt(0)" ::: "memory");
    else if (t == 6) asm volatile("s_waitcnt vmcnt(0) lgkmcnt(0)" ::: "memory");
    if (t < 7){ __builtin_amdgcn_s_barrier(); FENCE; }
  }

  #pragma unroll
  for (int mf = 0; mf < 2; mf++){
    #pragma unroll
    for (int nf = 0; nf < 4; nf++){
      int n = n0 + wn*64 + nf*16 + (l & 15);
      float bi = bias[n];
      int h_ = n >> 6, d_ = n & 63;
      if (z == 2){
        int mb = m0 + wm*32 + mf*16 + (l >> 4)*4;
        int b_ = mb >> 11, s_ = mb & 2047;
        uint2 o;
        o.x = (uint32_t)f2bf(acc[mf][nf][0] + bi) | ((uint32_t)f2bf(acc[mf][nf][1] + bi) << 16);
        o.y = (uint32_t)f2bf(acc[mf][nf][2] + bi) | ((uint32_t)f2bf(acc[mf][nf][3] + bi) << 16);
        *reinterpret_cast<uint2*>(&Vtp[((long)((b_*8 + h_)*64 + d_))*2048 + s_]) = o;
      } else {
        u16* outp = z == 0 ? Qp : Kp;
        #pragma unroll
        for (int r = 0; r < 4; r++){
          int m = m0 + wm*32 + mf*16 + (l >> 4)*4 + r;
          int b_ = m >> 11, s_ = m & 2047;
          outp[((long)((b_*8 + h_)*2048 + s_))*64 + d_] = f2bf((acc[mf][nf][r] + bi)*oscale);
        }
      }
    }
  }
}

// ---------------- output GEMM: 3-buffer counted-vmcnt pipeline ----------------
__global__ __launch_bounds__(512)
void k_gemm_ao(const u16* __restrict__ A, const u16* __restrict__ W,
               const float* __restrict__ bias2, float* __restrict__ outp)
{
  __shared__ __align__(16) u16 As[3][128*64];
  __shared__ __align__(16) u16 Bs[3][128*64];
  const int tid = threadIdx.x;
  const int w = tid >> 6, l = tid & 63;
  const int wm = w & 3, wn = w >> 2;
  const int m0 = blockIdx.x * 128, n0 = blockIdx.y * 128;
  const int srow = l >> 3, sslot = l & 7;

  f32x4 acc[2][4];
  #pragma unroll
  for (int i = 0; i < 2; i++)
    #pragma unroll
    for (int j = 0; j < 4; j++)
      #pragma unroll
      for (int r = 0; r < 4; r++) acc[i][j][r] = 0.f;

  auto STAGE = [&](int buf, int kt){
    #pragma unroll
    for (int i = 0; i < 2; i++){
      int r = w*16 + i*8 + srow;
      int scol = (sslot ^ (r & 7)) * 8;
      int m = m0 + r, k = kt + scol;
      long ga = ((long)(((m >> 11)*8 + (k >> 6))*2048 + (m & 2047)))*64 + (k & 63);
      __builtin_amdgcn_global_load_lds(GPTR(A + ga), LPTR(&As[buf][(w*16 + i*8)*64]), 16, 0, 0);
      long gb = (long)(n0 + r)*D + kt + scol;
      __builtin_amdgcn_global_load_lds(GPTR(W + gb), LPTR(&Bs[buf][(w*16 + i*8)*64]), 16, 0, 0);
    }
  };

  STAGE(0, 0); STAGE(1, 64);
  asm volatile("s_waitcnt vmcnt(4)" ::: "memory");
  __builtin_amdgcn_s_barrier();
  FENCE;

  #pragma unroll
  for (int t = 0; t < 8; t++){
    const int buf = t % 3;
    if (t + 2 < 8) STAGE((t + 2) % 3, (t + 2)*64);
    #pragma unroll
    for (int ks = 0; ks < 2; ks++){
      short8 af[2];
      #pragma unroll
      for (int mf = 0; mf < 2; mf++){
        int row = wm*32 + mf*16 + (l & 15);
        int cw = (ks*4 + (l >> 4)) ^ (row & 7);
        af[mf] = *reinterpret_cast<const short8*>(&As[buf][(row*8 + cw)*8]);
      }
      #pragma unroll
      for (int nf = 0; nf < 4; nf++){
        int row = wn*64 + nf*16 + (l & 15);
        int cw = (ks*4 + (l >> 4)) ^ (row & 7);
        short8 bf = *reinterpret_cast<const short8*>(&Bs[buf][(row*8 + cw)*8]);
        #pragma unroll
        for (int mf = 0; mf < 2; mf++)
          acc[mf][nf] = __builtin_amdgcn_mfma_f32_16x16x32_bf16(af[mf], bf, acc[mf][nf], 0, 0, 0);
      }
    }
    if (t < 7){
      if (t < 6) asm volatile("s_waitcnt vmcnt(4)" ::: "memory");
      else       asm volatile("s_waitcnt vmcnt(0)" ::: "memory");
      __builtin_amdgcn_s_barrier();
      FENCE;
    }
  }

  #pragma unroll
  for (int mf = 0; mf < 2; mf++)
    #pragma unroll
    for (int nf = 0; nf < 4; nf++){
      int n = n0 + wn*64 + nf*16 + (l & 15);
      float bi = bias2[(m0 >> 11)*512 + n];
      #pragma unroll
      for (int r = 0; r < 4; r++){
        int m = m0 + wm*32 + mf*16 + (l >> 4)*4 + r;
        outp[(long)m*D + n] = acc[mf][nf][r] + bi;
      }
    }
}

// ---------------- SV[bh][d] = sum_t Vt[bh][d][t] ----------------
__global__ __launch_bounds__(256)
void k_sumv(const u16* __restrict__ Vt, float* __restrict__ SV){
  const int w = threadIdx.x >> 6, l = threadIdx.x & 63;
  const int row = blockIdx.x*4 + w;
  const u16* src = Vt + (long)row * S;
  float s = 0.f;
  #pragma unroll
  for (int j = 0; j < 4; j++){
    short8 v = *reinterpret_cast<const short8*>(&src[j*512 + l*8]);
    #pragma unroll
    for (int e = 0; e < 8; e++)
      s += __uint_as_float(((uint32_t)(u16)v[e]) << 16);
  }
  #pragma unroll
  for (int m = 1; m < 64; m <<= 1) s += __shfl_xor(s, m, 64);
  if (l == 0) SV[row] = s;
}

// ---------------- bias2[b][n] = bo[n] + 0.5 * sum_k SV[b][k]*Wo[n][k] ----------------
__global__ __launch_bounds__(256)
void k_bias2(const float* __restrict__ SV, const float* __restrict__ Wo,
             const float* __restrict__ bo, float* __restrict__ bias2){
  const int w = threadIdx.x >> 6, l = threadIdx.x & 63;
  const int idx = blockIdx.x*4 + w;
  const int b = idx >> 9, n = idx & 511;
  float dot = 0.f;
  #pragma unroll
  for (int j = 0; j < 2; j++){
    float4 wv = *reinterpret_cast<const float4*>(&Wo[(long)n*512 + l*8 + j*4]);
    float4 sv = *reinterpret_cast<const float4*>(&SV[b*512 + l*8 + j*4]);
    dot += wv.x*sv.x + wv.y*sv.y + wv.z*sv.z + wv.w*sv.w;
  }
  #pragma unroll
  for (int m = 1; m < 64; m <<= 1) dot += __shfl_xor(dot, m, 64);
  if (l == 0) bias2[idx] = bo[n] + 0.5f * dot;
}

// ================ flash: paf-pipelined, macro codegen; (512,2) -> 256-reg cap ================
// AO = 0.25 * softmax(K.(Q*C2)) V ; 512 blocks = bh(32 fastest) x qt(16 of 128 rows)
// body(t): vmcnt(2); barrier; STAGE(t+2); QK(t); PV(t-1)[indep MFMA || EXP]; EXPPACK(t)

#define MFMA32(A_, B_, C_) __builtin_amdgcn_mfma_f32_32x32x16_bf16(A_, B_, C_, 0, 0, 0)

#define QKM(BUF_, SACC_) { \
    const u16* KT_ = KB + (BUF_)*2048; \
    short8 k0_ = *reinterpret_cast<const short8*>(KT_ + koff[0]); \
    short8 k1_ = *reinterpret_cast<const short8*>(KT_ + koff[1]); \
    short8 k2_ = *reinterpret_cast<const short8*>(KT_ + koff[2]); \
    short8 k3_ = *reinterpret_cast<const short8*>(KT_ + koff[3]); \
    __builtin_amdgcn_s_setprio(1); \
    SACC_ = MFMA32(k0_, qfr[0], SACC_); \
    SACC_ = MFMA32(k1_, qfr[1], SACC_); \
    SACC_ = MFMA32(k2_, qfr[2], SACC_); \
    SACC_ = MFMA32(k3_, qfr[3], SACC_); \
    __builtin_amdgcn_s_setprio(0); }

#define PVM(BUF_, P0_, P1_) { \
    const u16* VT_ = VB + (BUF_)*2048; \
    short8 v0_ = *reinterpret_cast<const short8*>(VT_ + voff[0]); \
    short8 v1_ = *reinterpret_cast<const short8*>(VT_ + voff[1]); \
    short8 v2_ = *reinterpret_cast<const short8*>(VT_ + voff[2]); \
    short8 v3_ = *reinterpret_cast<const short8*>(VT_ + voff[3]); \
    __builtin_amdgcn_s_setprio(1); \
    oacc0 = MFMA32(P0_, v0_, oacc0); \
    oacc1 = MFMA32(P0_, v1_, oacc1); \
    oacc0 = MFMA32(P1_, v2_, oacc0); \
    oacc1 = MFMA32(P1_, v3_, oacc1); \
    __builtin_amdgcn_s_setprio(0); }

#define EXPM(SACC_, P0_, P1_) { \
    uint32_t pk_[8]; float s0_ = 0.f, s1_ = 0.f; \
    _Pragma("unroll") \
    for (int j_ = 0; j_ < 8; j_++){ \
      float e0_ = __builtin_amdgcn_exp2f(SACC_[2*j_]); \
      float e1_ = __builtin_amdgcn_exp2f(SACC_[2*j_+1]); \
      if (j_ & 1) s1_ += e0_ + e1_; else s0_ += e0_ + e1_; \
      pk_[j_] = cvt_pk_bf16(e0_, e1_); \
    } \
    lsum += s0_ + s1_; \
    { auto q1_ = __builtin_amdgcn_permlane32_swap(pk_[0], pk_[2], false, false); \
      auto q2_ = __builtin_amdgcn_permlane32_swap(pk_[1], pk_[3], false, false); \
      u32x4 a_ = { (uint32_t)q1_[0], (uint32_t)q2_[0], (uint32_t)q1_[1], (uint32_t)q2_[1] }; \
      P0_ = __builtin_bit_cast(short8, a_); } \
    { auto q1_ = __builtin_amdgcn_permlane32_swap(pk_[4], pk_[6], false, false); \
      auto q2_ = __builtin_amdgcn_permlane32_swap(pk_[5], pk_[7], false, false); \
      u32x4 a_ = { (uint32_t)q1_[0], (uint32_t)q2_[0], (uint32_t)q1_[1], (uint32_t)q2_[1] }; \
      P1_ = __builtin_bit_cast(short8, a_); } }

#define BODYM(VMC_, DOSTG_, QB_, PVB_, PE0_, PE1_, PP0_, PP1_) { \
    asm volatile("s_waitcnt vmcnt(" VMC_ ")" ::: "memory"); \
    __builtin_amdgcn_s_barrier(); \
    FENCE; \
    if (DOSTG_) STAGE(((QB_) + 2) & 3); \
    f32x16 sacc_ = {0.f,0.f,0.f,0.f,0.f,0.f,0.f,0.f,0.f,0.f,0.f,0.f,0.f,0.f,0.f,0.f}; \
    QKM(QB_, sacc_); \
    PVM(PVB_, PP0_, PP1_); \
    EXPM(sacc_, PE0_, PE1_); }

__global__ __launch_bounds__(512, 2)
void k_flash(const u16* __restrict__ Qp, const u16* __restrict__ Kp,
             const u16* __restrict__ Vt, u16* __restrict__ AO)
{
  __shared__ __align__(16) u16 Ks[2][4][32*64];   // [group][buf] 32 keys x 64 d
  __shared__ __align__(16) u16 Vs[2][4][64*32];   // [group][buf] 64 d x 32 keys
  const int tid = threadIdx.x, w = tid >> 6, l = tid & 63;
  const int g = w >> 2, w4 = w & 3;
  const int bh = blockIdx.x & 31, qt = blockIdx.x >> 5;   // qt 0..15
  const u16* Qb = Qp + (long)bh * S * DH;
  const int hi = l >> 5, ln = l & 31;

  short8 qfr[4];   // Q*C2 (scale folded in projection)
  #pragma unroll
  for (int c = 0; c < 4; c++){
    int row = qt*128 + w4*32 + ln;
    qfr[c] = *reinterpret_cast<const short8*>(&Qb[(long)row*DH + c*16 + hi*8]);
  }

  // lane-constant LDS read offsets (u16 units within one buf)
  int koff[4], voff[4];
  #pragma unroll
  for (int c = 0; c < 4; c++)
    koff[c] = ln*64 + (((2*c + hi) ^ ((ln ^ (ln >> 3)) & 7))*8);
  #pragma unroll
  for (int ch = 0; ch < 2; ch++)
    #pragma unroll
    for (int nf = 0; nf < 2; nf++){
      int row = nf*32 + ln;
      voff[ch*2 + nf] = row*32 + (((2*ch + hi) ^ ((row ^ (row >> 2)) & 3))*8);
    }

  // staging: source offsets folded into the walking pointers
  const int rK = w4*8 + (l >> 3), sK = l & 7;
  const int rV = w4*16 + (l >> 2), sV = l & 3;
  const u16* kptr = Kp + (long)bh*S*DH + g*2048
                  + (long)rK*64 + ((sK ^ ((rK ^ (rK >> 3)) & 7))*8);
  const u16* vptr = Vt + (long)bh*DH*S + g*32
                  + (long)rV*S  + ((sV ^ ((rV ^ (rV >> 2)) & 3))*8);

  auto STAGE = [&](int buf){
    __builtin_amdgcn_global_load_lds(GPTR(kptr), LPTR(&Ks[g][buf][w4*512]), 16, 0, 0);
    __builtin_amdgcn_global_load_lds(GPTR(vptr), LPTR(&Vs[g][buf][w4*512]), 16, 0, 0);
    kptr += 4096;   // next tile for this group (64 keys forward)
    vptr += 64;
  };

  f32x16 oacc0, oacc1;
  #pragma unroll
  for (int r = 0; r < 16; r++){ oacc0[r] = 0.f; oacc1[r] = 0.f; }
  float lsum = 0.f;
  short8 pafA0, pafA1, pafB0, pafB1;

  const u16* KB = &Ks[g][0][0];
  const u16* VB = &Vs[g][0][0];

  // prologue: depth-2 prefetch; t=0 (even): QK, EXP -> pafA (no PV)
  STAGE(0); STAGE(1);
  asm volatile("s_waitcnt vmcnt(2)" ::: "memory");
  __builtin_amdgcn_s_barrier();
  FENCE;
  STAGE(2);
  {
    f32x16 sacc_ = {0.f,0.f,0.f,0.f,0.f,0.f,0.f,0.f,0.f,0.f,0.f,0.f,0.f,0.f,0.f,0.f};
    QKM(0, sacc_);
    EXPM(sacc_, pafA0, pafA1);
  }

  // main loop: t = 1..28 (7 chunks of 4; buf pattern 1,2,3,0; parity O,E,O,E)
  #pragma unroll 1
  for (int tb = 0; tb < 7; tb++){
    BODYM("2", true, 1, 0, pafB0, pafB1, pafA0, pafA1);   // t odd : EXP->B, PV uses A
    BODYM("2", true, 2, 1, pafA0, pafA1, pafB0, pafB1);   // t even: EXP->A, PV uses B
    BODYM("2", true, 3, 2, pafB0, pafB1, pafA0, pafA1);
    BODYM("2", true, 0, 3, pafA0, pafA1, pafB0, pafB1);
  }
  // tail: t=29 (odd, buf 1, stage 31), t=30 (even, buf 2), t=31 (odd, buf 3)
  BODYM("2", true,  1, 0, pafB0, pafB1, pafA0, pafA1);    // t=29
  BODYM("2", false, 2, 1, pafA0, pafA1, pafB0, pafB1);    // t=30
  BODYM("0", false, 3, 2, pafB0, pafB1, pafA0, pafA1);    // t=31
  PVM(3, pafB0, pafB1);                                   // PV(31)

  __syncthreads();   // all compute done before LDS reuse

  // cross-group combine in LDS
  lsum += __shfl_xor(lsum, 32, 64);
  float* OB = (float*)Ks;    // 4 waves x 32 qrow x 64 d = 32 KB
  float* LB = (float*)Vs;
  if (g == 1){
    #pragma unroll
    for (int r = 0; r < 16; r++){
      int qrow = (r & 3) + 8*(r >> 2) + 4*hi;
      OB[w4*2048 + qrow*64 + ln]      = oacc0[r];
      OB[w4*2048 + qrow*64 + 32 + ln] = oacc1[r];
    }
    if (hi == 0) LB[w4*32 + ln] = lsum;
  }
  __syncthreads();
  if (g == 0){
    float l2 = LB[w4*32 + ln];
    float linv = 0.25f / (lsum + l2);   // valid for qrow = ln
    #pragma unroll
    for (int r = 0; r < 16; r++){
      int qrow = (r & 3) + 8*(r >> 2) + 4*hi;
      float sc = __shfl(linv, qrow, 64);
      int s_ = qt*128 + w4*32 + qrow;
      float o0 = oacc0[r] + OB[w4*2048 + qrow*64 + ln];
      float o1 = oacc1[r] + OB[w4*2048 + qrow*64 + 32 + ln];
      AO[((long)bh*S + s_)*DH + ln]      = f2bf(o0 * sc);
      AO[((long)bh*S + s_)*DH + 32 + ln] = f2bf(o1 * sc);
    }
  }
}

// ---------------- launch ----------------
extern "C" void kernel_launch(void* const* d_in, const int* in_sizes, int n_in,
                              void* d_out, int out_size, void* d_ws, size_t ws_size,
                              hipStream_t stream)
{
  const float* query = (const float*)d_in[0];
  const float* key_  = (const float*)d_in[1];
  const float* value = (const float*)d_in[2];
  const float* Wq = (const float*)d_in[3];
  const float* bq = (const float*)d_in[4];
  const float* Wk = (const float*)d_in[5];
  const float* bk = (const float*)d_in[6];
  const float* Wv = (const float*)d_in[7];
  const float* bv = (const float*)d_in[8];
  const float* Wo = (const float*)d_in[9];
  const float* bo = (const float*)d_in[10];

  char* ws = (char*)d_ws;
  const size_t XSZ = (size_t)8192 * 512 * 2;   // 8 MiB
  const size_t WSZ = (size_t)512 * 512 * 2;    // 512 KiB
  u16* AO  = (u16*)(ws);
  u16* wqb = (u16*)(ws + XSZ);                 // wq|wk|wv|wo contiguous
  u16* wob = (u16*)(ws + XSZ + 3*WSZ);
  u16* Qp  = (u16*)(ws + XSZ + 4*WSZ);
  u16* Kp  = (u16*)(ws + 2*XSZ + 4*WSZ);
  u16* Vtp = (u16*)(ws + 3*XSZ + 4*WSZ);
  float* SV    = (float*)(ws + 4*XSZ + 4*WSZ);
  float* bias2 = (float*)(ws + 4*XSZ + 4*WSZ + 8192);

  k_cvtw<<<(4<<16)/256, 256, 0, stream>>>(Wq, Wk, Wv, Wo, wqb);

  dim3 gq(64, 4, 3);
  k_gemm_qkv<<<gq, 512, 0, stream>>>(query, key_, value, wqb, bq, bk, bv, Qp, Kp, Vtp);

  k_sumv <<<512, 256, 0, stream>>>(Vtp, SV);
  k_bias2<<<512, 256, 0, stream>>>(SV, Wo, bo, bias2);

  k_flash<<<512, 512, 0, stream>>>(Qp, Kp, Vtp, AO);

  dim3 gg(64, 4);
  k_gemm_ao<<<gg, 512, 0, stream>>>(AO, wob, bias2, (float*)d_out);
}